// Round 13
// baseline (35.016 us; speedup 1.0000x reference)
//
#include <hip/hip_runtime.h>

// Y[b,e,k,j] = sum_i X[b, ind[b,e,k], i] * W[e,i,j]
// X:[B,T,I] f32, ind:[B,E,K] int32, W:[E,I,J] f32 -> Y:[B,E,K,J] f32
#define B_ 8
#define T_ 8192
#define I_ 128
#define E_ 16
#define J_ 128
#define K_ 1024

typedef unsigned short u16;
typedef unsigned int   u32;
typedef __attribute__((ext_vector_type(8))) short s8v;   // 8 bf16 = 4 VGPRs
typedef __attribute__((ext_vector_type(4))) float f4v;   // MFMA accumulator

__device__ __forceinline__ u16 f2bf(float f) {
    union { float f; u32 u; } v; v.f = f;
    const u32 u = v.u;
    return (u16)((u + 0x7fffu + ((u >> 16) & 1u)) >> 16);  // RNE, branch-free
}

// ---- Prepass (r8 verbatim): Wt[e][j][i] = bf16(W[e][i][j]), linear ----
__global__ void convert_wt(const float* __restrict__ W, u16* __restrict__ Wt) {
    const int t  = blockIdx.x * 256 + threadIdx.x;  // 32768 threads
    const int o8 = t * 8;                           // 8 outputs along i
    const int e  = o8 >> 14;
    const int r  = o8 & 16383;
    const int j  = r >> 7;
    const int i0 = r & 127;
    const float* Wp = W + e * (I_ * J_) + j;        // column j of W[e]
    s8v o;
#pragma unroll
    for (int u = 0; u < 8; ++u)
        o[u] = (short)f2bf(Wp[(i0 + u) * J_]);
    *reinterpret_cast<s8v*>(Wt + o8) = o;
}

// ---- Main (PRE): barrier-free, LDS-free register-W kernel ----
// 256 threads = 4 waves: wave = (rh = 128-row half, jh = j-half).
// Per wave: W j-half in 64 VGPRs (16 dwordx4, L2-hot), then 8 stripes of
// 16 k-rows: per-lane direct X loads -> in-reg cvt -> 16 MFMA -> 16 stores.
// No __syncthreads after launch, no LDS: waves free-run, phases mix across
// the 12 resident waves/CU -> memory system stays busy.
__global__ __launch_bounds__(256, 3)
void gather_mfma_regw(const float* __restrict__ X, const int* __restrict__ ind,
                      const u16* __restrict__ Wt, float* __restrict__ Y) {
    const int t    = threadIdx.x;
    const int wave = t >> 6;
    const int lane = t & 63;

    // XCD b-affinity: grid=512, XCD x gets bid 64x..64x+63 -> b = x.
    const int orig = blockIdx.x;
    const int bid  = (orig & 7) * 64 + (orig >> 3);
    const int kq = bid & 3;              // quarter of K: 256 rows
    const int be = bid >> 2;
    const int e  = be & (E_ - 1);
    const int b  = be >> 4;

    const int rh  = wave >> 1;           // 128-row half of the 256-row range
    const int jh  = wave & 1;            // j half (64 cols)
    const int g   = lane >> 4;
    const int l15 = lane & 15;

    // ---- W prologue: lane (g,l15) holds B-frag W[j=jh*64+nj*16+l15][i=s*32+g*8..+7]
    const u16* Wte = Wt + (size_t)e * (I_ * J_);
    s8v wf[4][4];
#pragma unroll
    for (int nj = 0; nj < 4; ++nj)
#pragma unroll
        for (int s = 0; s < 4; ++s)
            wf[nj][s] = *reinterpret_cast<const s8v*>(
                Wte + (size_t)(jh * 64 + nj * 16 + l15) * I_ + s * 32 + g * 8);

    const int rbase = kq * 256 + rh * 128;
    // Token indices for all 8 stripes (lane l15 -> row l15 of each stripe)
    int idx8[8];
#pragma unroll
    for (int st = 0; st < 8; ++st)
        idx8[st] = ind[(size_t)be * K_ + rbase + st * 16 + l15];

    const float* Xb = X + (size_t)b * T_ * I_;
    float* Ybase = Y + ((size_t)be * K_ + rbase) * J_ + jh * 64;

#pragma unroll
    for (int st = 0; st < 8; ++st) {
        // A-frag source: row tok, i-chunk s*32+g*8 (4 g-lanes = 128B/row span)
        const float4* xr = reinterpret_cast<const float4*>(Xb + (size_t)idx8[st] * I_);
        float4 xv[8];
#pragma unroll
        for (int s = 0; s < 4; ++s) {
            xv[2 * s]     = xr[s * 8 + g * 2];
            xv[2 * s + 1] = xr[s * 8 + g * 2 + 1];
        }
        s8v xf[4];
#pragma unroll
        for (int s = 0; s < 4; ++s) {
            const float4 a = xv[2 * s], c = xv[2 * s + 1];
            xf[s][0] = (short)f2bf(a.x); xf[s][1] = (short)f2bf(a.y);
            xf[s][2] = (short)f2bf(a.z); xf[s][3] = (short)f2bf(a.w);
            xf[s][4] = (short)f2bf(c.x); xf[s][5] = (short)f2bf(c.y);
            xf[s][6] = (short)f2bf(c.z); xf[s][7] = (short)f2bf(c.w);
        }

        f4v acc[4];
#pragma unroll
        for (int nj = 0; nj < 4; ++nj)
#pragma unroll
            for (int rr = 0; rr < 4; ++rr) acc[nj][rr] = 0.f;

#pragma unroll
        for (int s = 0; s < 4; ++s)
#pragma unroll
            for (int nj = 0; nj < 4; ++nj)
                acc[nj] = __builtin_amdgcn_mfma_f32_16x16x32_bf16(xf[s], wf[nj][s], acc[nj], 0, 0, 0);

        // Store (r8-verified mapping): D col(l15)=j, row(4g+rr)=k-row of stripe
        float* Yst = Ybase + (size_t)(st * 16 + g * 4) * J_;
#pragma unroll
        for (int nj = 0; nj < 4; ++nj) {
            const int col = nj * 16 + l15;
#pragma unroll
            for (int rr = 0; rr < 4; ++rr)
                Yst[(size_t)rr * J_ + col] = acc[nj][rr];
        }
    }
}

// ---- Fallback (no workspace): r12 staged-LDS kernel, W f32 inline ----
__global__ __launch_bounds__(512, 4)
void gather_mfma_lds(const float* __restrict__ X, const int* __restrict__ ind,
                     const float* __restrict__ Wsrc, float* __restrict__ Y) {
    __shared__ u16 WsT[I_ * J_];
    __shared__ u16 Xs[128 * I_];

    const int t    = threadIdx.x;
    const int wave = t >> 6;
    const int lane = t & 63;

    const int orig = blockIdx.x;
    const int bid  = (orig & 7) * 128 + (orig >> 3);
    const int kt = bid & 7;
    const int be = bid >> 3;
    const int e  = be & (E_ - 1);
    const int b  = be >> 4;
    const int k0 = kt * 128;

    {
        const float* We = Wsrc + (size_t)e * (I_ * J_);
#pragma unroll
        for (int u = 0; u < 8; ++u) {
            const int f4i = t + 512 * u;
            const int i   = f4i >> 5;
            const int j0  = (f4i & 31) * 4;
            const float4 w4 = reinterpret_cast<const float4*>(We)[f4i];
            const float ws[4] = {w4.x, w4.y, w4.z, w4.w};
#pragma unroll
            for (int q = 0; q < 4; ++q) {
                const int j = j0 + q;
                *(u16*)((char*)WsT + ((j * 256 + i * 2) ^ ((j & 7) << 4))) = f2bf(ws[q]);
            }
        }
    }
    {
        const int r   = t >> 2;
        const int q   = t & 3;
        const int idx = ind[(size_t)be * K_ + k0 + r];
        const float4* Xr = reinterpret_cast<const float4*>(X + ((size_t)b * T_ + idx) * I_) + q * 8;
        const int sx = (r & 7) << 4;
        char* xrow = (char*)Xs + r * 256;
#pragma unroll
        for (int u = 0; u < 4; ++u) {
            const float4 a = Xr[2 * u], c = Xr[2 * u + 1];
            s8v o;
            o[0] = (short)f2bf(a.x); o[1] = (short)f2bf(a.y);
            o[2] = (short)f2bf(a.z); o[3] = (short)f2bf(a.w);
            o[4] = (short)f2bf(c.x); o[5] = (short)f2bf(c.y);
            o[6] = (short)f2bf(c.z); o[7] = (short)f2bf(c.w);
            *reinterpret_cast<s8v*>(xrow + ((q * 64 + u * 16) ^ sx)) = o;
        }
    }
    __syncthreads();

    const int rq  = wave >> 1;
    const int jh  = wave & 1;
    const int g   = lane >> 4;
    const int l15 = lane & 15;
    const int sx  = (lane & 7) << 4;

    f4v acc[2][4];
#pragma unroll
    for (int tr = 0; tr < 2; ++tr)
#pragma unroll
        for (int n = 0; n < 4; ++n)
#pragma unroll
            for (int r = 0; r < 4; ++r) acc[tr][n][r] = 0.f;

    const char* xb = (const char*)Xs  + (size_t)(rq * 32 + l15) * 256;
    const char* wb = (const char*)WsT + (size_t)(jh * 64 + l15) * 256;
#pragma unroll
    for (int s = 0; s < 4; ++s) {
        const int off = (s * 64 + g * 16) ^ sx;
        const s8v a0 = *reinterpret_cast<const s8v*>(xb + off);
        const s8v a1 = *reinterpret_cast<const s8v*>(xb + 16 * 256 + off);
#pragma unroll
        for (int n = 0; n < 4; ++n) {
            const s8v bf = *reinterpret_cast<const s8v*>(wb + n * 16 * 256 + off);
            acc[0][n] = __builtin_amdgcn_mfma_f32_16x16x32_bf16(a0, bf, acc[0][n], 0, 0, 0);
            acc[1][n] = __builtin_amdgcn_mfma_f32_16x16x32_bf16(a1, bf, acc[1][n], 0, 0, 0);
        }
    }

    float* Yb = Y + ((size_t)be * K_ + k0) * J_;
#pragma unroll
    for (int tr = 0; tr < 2; ++tr)
#pragma unroll
        for (int n = 0; n < 4; ++n) {
            const int col = jh * 64 + n * 16 + l15;
            const int row0 = rq * 32 + tr * 16 + g * 4;
#pragma unroll
            for (int r = 0; r < 4; ++r)
                Yb[(size_t)(row0 + r) * J_ + col] = acc[tr][n][r];
        }
}

extern "C" void kernel_launch(void* const* d_in, const int* in_sizes, int n_in,
                              void* d_out, int out_size, void* d_ws, size_t ws_size,
                              hipStream_t stream) {
    (void)in_sizes; (void)n_in; (void)out_size;
    const float* X   = (const float*)d_in[0];
    const int*   ind = (const int*)d_in[1];
    const float* W   = (const float*)d_in[2];
    float*       Y   = (float*)d_out;

    const size_t wt_bytes = (size_t)E_ * I_ * J_ * sizeof(u16);  // 512 KB

    if (ws_size >= wt_bytes && d_ws != nullptr) {
        u16* Wt = (u16*)d_ws;
        hipLaunchKernelGGL(convert_wt, dim3(E_ * I_ * J_ / (256 * 8)), dim3(256), 0, stream, W, Wt);
        hipLaunchKernelGGL(gather_mfma_regw, dim3(B_ * E_ * 4), dim3(256), 0, stream,
                           X, ind, Wt, Y);   // grid 512, all-resident
    } else {
        hipLaunchKernelGGL(gather_mfma_lds, dim3(B_ * E_ * (K_ / 128)), dim3(512), 0, stream,
                           X, ind, W, Y);
    }
}

// Round 14
// 33.572 us; speedup vs baseline: 1.0430x; 1.0430x over previous
//
#include <hip/hip_runtime.h>

// Y[b,e,k,j] = sum_i X[b, ind[b,e,k], i] * W[e,i,j]
// X:[B,T,I] f32, ind:[B,E,K] int32, W:[E,I,J] f32 -> Y:[B,E,K,J] f32
#define B_ 8
#define T_ 8192
#define I_ 128
#define E_ 16
#define J_ 128
#define K_ 1024

typedef unsigned short u16;
typedef unsigned int   u32;
typedef __attribute__((ext_vector_type(8))) short s8v;   // 8 bf16 = 4 VGPRs
typedef __attribute__((ext_vector_type(4))) float f4v;   // MFMA accumulator

__device__ __forceinline__ u16 f2bf(float f) {
    union { float f; u32 u; } v; v.f = f;
    const u32 u = v.u;
    return (u16)((u + 0x7fffu + ((u >> 16) & 1u)) >> 16);  // RNE, branch-free
}

// ---- Prepass (r8 verbatim): Wt[e][j][i] = bf16(W[e][i][j]), linear ----
__global__ void convert_wt(const float* __restrict__ W, u16* __restrict__ Wt) {
    const int t  = blockIdx.x * 256 + threadIdx.x;  // 32768 threads
    const int o8 = t * 8;                           // 8 outputs along i
    const int e  = o8 >> 14;
    const int r  = o8 & 16383;
    const int j  = r >> 7;
    const int i0 = r & 127;
    const float* Wp = W + e * (I_ * J_) + j;        // column j of W[e]
    s8v o;
#pragma unroll
    for (int u = 0; u < 8; ++u)
        o[u] = (short)f2bf(Wp[(i0 + u) * J_]);
    *reinterpret_cast<s8v*>(Wt + o8) = o;
}

// Load stripe st's A-fragment source: lane (g,l15) reads X[idx[st]] floats
// [s*32+g*8 .. +7] as 2 float4 per s (4 g-lanes cover a 128B row span).
#define LOAD_STRIPE(buf, st) {                                                  \
    const float4* xr_ = reinterpret_cast<const float4*>(Xb + (size_t)idx[st] * I_); \
    _Pragma("unroll")                                                           \
    for (int u_ = 0; u_ < 8; ++u_)                                              \
        buf[u_] = xr_[(u_ >> 1) * 8 + g * 2 + (u_ & 1)];                        \
}

// Convert + 16 MFMA + 16 scalar stores for stripe st from buf.
#define COMPUTE_STORE(buf, st) {                                                \
    f4v acc_[4];                                                                \
    _Pragma("unroll")                                                           \
    for (int n_ = 0; n_ < 4; ++n_)                                              \
        _Pragma("unroll")                                                       \
        for (int r_ = 0; r_ < 4; ++r_) acc_[n_][r_] = 0.f;                      \
    _Pragma("unroll")                                                           \
    for (int s_ = 0; s_ < 4; ++s_) {                                            \
        const float4 a_ = buf[2 * s_], c_ = buf[2 * s_ + 1];                    \
        s8v xf_;                                                                \
        xf_[0] = (short)f2bf(a_.x); xf_[1] = (short)f2bf(a_.y);                 \
        xf_[2] = (short)f2bf(a_.z); xf_[3] = (short)f2bf(a_.w);                 \
        xf_[4] = (short)f2bf(c_.x); xf_[5] = (short)f2bf(c_.y);                 \
        xf_[6] = (short)f2bf(c_.z); xf_[7] = (short)f2bf(c_.w);                 \
        const int off_ = (s_ * 64 + g * 16) ^ sx;                               \
        _Pragma("unroll")                                                       \
        for (int n_ = 0; n_ < 4; ++n_) {                                        \
            const s8v bf_ = *reinterpret_cast<const s8v*>(wb + n_ * 16 * 256 + off_); \
            acc_[n_] = __builtin_amdgcn_mfma_f32_16x16x32_bf16(xf_, bf_, acc_[n_], 0, 0, 0); \
        }                                                                       \
    }                                                                           \
    float* Yst_ = Ybase + (size_t)((st) * 16 + g * 4) * J_;                     \
    _Pragma("unroll")                                                           \
    for (int n_ = 0; n_ < 4; ++n_) {                                            \
        const int col_ = n_ * 16 + l15;                                         \
        _Pragma("unroll")                                                       \
        for (int r_ = 0; r_ < 4; ++r_)                                          \
            Yst_[(size_t)r_ * J_ + col_] = acc_[n_][r_];                        \
    }                                                                           \
}

// ---- Main (PRE): W in LDS (one stage, ONE barrier); X per-lane direct with
// explicit ping-pong 1-deep prefetch; no Xs LDS, no staging convoy.
// 4 waves = (rh: 64-row half, jh: j-half); each wave 4 stripes of 16 rows.
// LDS 32KB -> 4 blocks/CU; VGPR ~110 -> launch_bounds(256,4) = 16 waves/CU.
__global__ __launch_bounds__(256, 4)
void gather_mfma_direct(const float* __restrict__ X, const int* __restrict__ ind,
                        const u16* __restrict__ Wt, float* __restrict__ Y) {
    __shared__ u16 WsT[I_ * J_];

    const int t    = threadIdx.x;
    const int wave = t >> 6;
    const int lane = t & 63;

    // XCD b-affinity: grid=1024, XCD x gets bid 128x..128x+127 -> b = x.
    const int orig = blockIdx.x;
    const int bid  = (orig & 7) * 128 + (orig >> 3);
    const int kt = bid & 7;              // 8 x 128-row tiles
    const int be = bid >> 3;
    const int e  = be & (E_ - 1);
    const int b  = be >> 4;
    const int k0 = kt * 128;

    // ---- Stage WsT (r8 verbatim): linear [j][i] image -> swizzled LDS ----
    {
        const s8v* Wg = reinterpret_cast<const s8v*>(Wt + (size_t)e * (I_ * J_));
#pragma unroll
        for (int u = 0; u < 8; ++u) {
            const int c   = t + 256 * u;          // 16B chunk id, 0..2047
            const int row = c >> 4;               // j
            const s8v v = Wg[c];
            *reinterpret_cast<s8v*>((char*)WsT + ((c * 16) ^ ((row & 7) << 4))) = v;
        }
    }
    __syncthreads();     // the ONLY barrier

    const int rh  = wave >> 1;
    const int jh  = wave & 1;
    const int g   = lane >> 4;
    const int l15 = lane & 15;
    const int sx  = (lane & 7) << 4;
    const char* wb = (const char*)WsT + (size_t)(jh * 64 + l15) * 256;

    const float* Xb = X + (size_t)b * T_ * I_;
    float* Ybase = Y + ((size_t)be * K_ + k0 + rh * 64) * J_ + jh * 64;

    // Token indices for the wave's 4 stripes (row l15 of each)
    const size_t indbase = (size_t)be * K_ + k0 + rh * 64 + l15;
    int idx[4];
#pragma unroll
    for (int st = 0; st < 4; ++st) idx[st] = ind[indbase + st * 16];

    float4 bufA[8], bufB[8];
    // Ping-pong: issue next stripe's loads before computing current.
    LOAD_STRIPE(bufA, 0);
    LOAD_STRIPE(bufB, 1);
    COMPUTE_STORE(bufA, 0);
    LOAD_STRIPE(bufA, 2);
    COMPUTE_STORE(bufB, 1);
    LOAD_STRIPE(bufB, 3);
    COMPUTE_STORE(bufA, 2);
    COMPUTE_STORE(bufB, 3);
}

// ---- Fallback (no workspace): r12 staged-LDS kernel, W f32 inline ----
__global__ __launch_bounds__(512, 4)
void gather_mfma_lds(const float* __restrict__ X, const int* __restrict__ ind,
                     const float* __restrict__ Wsrc, float* __restrict__ Y) {
    __shared__ u16 WsT[I_ * J_];
    __shared__ u16 Xs[128 * I_];

    const int t    = threadIdx.x;
    const int wave = t >> 6;
    const int lane = t & 63;

    const int orig = blockIdx.x;
    const int bid  = (orig & 7) * 128 + (orig >> 3);
    const int kt = bid & 7;
    const int be = bid >> 3;
    const int e  = be & (E_ - 1);
    const int b  = be >> 4;
    const int k0 = kt * 128;

    {
        const float* We = Wsrc + (size_t)e * (I_ * J_);
#pragma unroll
        for (int u = 0; u < 8; ++u) {
            const int f4i = t + 512 * u;
            const int i   = f4i >> 5;
            const int j0  = (f4i & 31) * 4;
            const float4 w4 = reinterpret_cast<const float4*>(We)[f4i];
            const float ws[4] = {w4.x, w4.y, w4.z, w4.w};
#pragma unroll
            for (int q = 0; q < 4; ++q) {
                const int j = j0 + q;
                *(u16*)((char*)WsT + ((j * 256 + i * 2) ^ ((j & 7) << 4))) = f2bf(ws[q]);
            }
        }
    }
    {
        const int r   = t >> 2;
        const int q   = t & 3;
        const int idx = ind[(size_t)be * K_ + k0 + r];
        const float4* Xr = reinterpret_cast<const float4*>(X + ((size_t)b * T_ + idx) * I_) + q * 8;
        const int sx = (r & 7) << 4;
        char* xrow = (char*)Xs + r * 256;
#pragma unroll
        for (int u = 0; u < 4; ++u) {
            const float4 a = Xr[2 * u], c = Xr[2 * u + 1];
            s8v o;
            o[0] = (short)f2bf(a.x); o[1] = (short)f2bf(a.y);
            o[2] = (short)f2bf(a.z); o[3] = (short)f2bf(a.w);
            o[4] = (short)f2bf(c.x); o[5] = (short)f2bf(c.y);
            o[6] = (short)f2bf(c.z); o[7] = (short)f2bf(c.w);
            *reinterpret_cast<s8v*>(xrow + ((q * 64 + u * 16) ^ sx)) = o;
        }
    }
    __syncthreads();

    const int rq  = wave >> 1;
    const int jh  = wave & 1;
    const int g   = lane >> 4;
    const int l15 = lane & 15;
    const int sx  = (lane & 7) << 4;

    f4v acc[2][4];
#pragma unroll
    for (int tr = 0; tr < 2; ++tr)
#pragma unroll
        for (int n = 0; n < 4; ++n)
#pragma unroll
            for (int r = 0; r < 4; ++r) acc[tr][n][r] = 0.f;

    const char* xb = (const char*)Xs  + (size_t)(rq * 32 + l15) * 256;
    const char* wb = (const char*)WsT + (size_t)(jh * 64 + l15) * 256;
#pragma unroll
    for (int s = 0; s < 4; ++s) {
        const int off = (s * 64 + g * 16) ^ sx;
        const s8v a0 = *reinterpret_cast<const s8v*>(xb + off);
        const s8v a1 = *reinterpret_cast<const s8v*>(xb + 16 * 256 + off);
#pragma unroll
        for (int n = 0; n < 4; ++n) {
            const s8v bf = *reinterpret_cast<const s8v*>(wb + n * 16 * 256 + off);
            acc[0][n] = __builtin_amdgcn_mfma_f32_16x16x32_bf16(a0, bf, acc[0][n], 0, 0, 0);
            acc[1][n] = __builtin_amdgcn_mfma_f32_16x16x32_bf16(a1, bf, acc[1][n], 0, 0, 0);
        }
    }

    float* Yb = Y + ((size_t)be * K_ + k0) * J_;
#pragma unroll
    for (int tr = 0; tr < 2; ++tr)
#pragma unroll
        for (int n = 0; n < 4; ++n) {
            const int col = jh * 64 + n * 16 + l15;
            const int row0 = rq * 32 + tr * 16 + g * 4;
#pragma unroll
            for (int r = 0; r < 4; ++r)
                Yb[(size_t)(row0 + r) * J_ + col] = acc[tr][n][r];
        }
}

extern "C" void kernel_launch(void* const* d_in, const int* in_sizes, int n_in,
                              void* d_out, int out_size, void* d_ws, size_t ws_size,
                              hipStream_t stream) {
    (void)in_sizes; (void)n_in; (void)out_size;
    const float* X   = (const float*)d_in[0];
    const int*   ind = (const int*)d_in[1];
    const float* W   = (const float*)d_in[2];
    float*       Y   = (float*)d_out;

    const size_t wt_bytes = (size_t)E_ * I_ * J_ * sizeof(u16);  // 512 KB

    if (ws_size >= wt_bytes && d_ws != nullptr) {
        u16* Wt = (u16*)d_ws;
        hipLaunchKernelGGL(convert_wt, dim3(E_ * I_ * J_ / (256 * 8)), dim3(256), 0, stream, W, Wt);
        hipLaunchKernelGGL(gather_mfma_direct, dim3(1024), dim3(256), 0, stream,
                           X, ind, Wt, Y);
    } else {
        hipLaunchKernelGGL(gather_mfma_lds, dim3(1024), dim3(512), 0, stream,
                           X, ind, W, Y);
    }
}

// Round 15
// 30.743 us; speedup vs baseline: 1.1390x; 1.0920x over previous
//
#include <hip/hip_runtime.h>

// Y[b,e,k,j] = sum_i X[b, ind[b,e,k], i] * W[e,i,j]
// X:[B,T,I] f32, ind:[B,E,K] int32, W:[E,I,J] f32 -> Y:[B,E,K,J] f32
#define B_ 8
#define T_ 8192
#define I_ 128
#define E_ 16
#define J_ 128
#define K_ 1024
#define ROWS 128   // k-rows per block (512 threads)

typedef unsigned short u16;
typedef unsigned int   u32;
typedef __attribute__((ext_vector_type(8))) short s8v;   // 8 bf16 = 4 VGPRs
typedef __attribute__((ext_vector_type(4))) float f4v;   // MFMA accumulator

__device__ __forceinline__ u16 f2bf(float f) {
    union { float f; u32 u; } v; v.f = f;
    const u32 u = v.u;
    return (u16)((u + 0x7fffu + ((u >> 16) & 1u)) >> 16);  // RNE, branch-free
}

__device__ __forceinline__ void gload_lds16(const void* g, void* l) {
    __builtin_amdgcn_global_load_lds(
        (const __attribute__((address_space(1))) u32*)g,
        (__attribute__((address_space(3))) u32*)l, 16, 0, 0);
}

// ---- Prepass (r5 form): PRE-SWIZZLED bf16 W^T image per expert ----
// Image chunk c (16B): j = c>>4, i0 = (c&15)*8, holds bf16 W[e][i0..i0+7][j]
// at byte offset (c*16) ^ ((j&7)<<4). 64 blocks = (e, j-quarter); coalesced
// float4 reads, padded LDS transpose, coalesced 16B image writes.
__global__ void convert_wt(const float* __restrict__ W, u16* __restrict__ Wt) {
    __shared__ float Wf[I_ * 33];        // [i][jl], jl=0..31, padded
    const int bid = blockIdx.x;          // e*4 + jq
    const int e   = bid >> 2;
    const int j0  = (bid & 3) * 32;
    const int t   = threadIdx.x;
    const float* We = W + (size_t)e * (I_ * J_);
#pragma unroll
    for (int u = 0; u < 4; ++u) {
        const int f4 = t + 256 * u;      // 0..1023
        const int i  = f4 >> 3;
        const int c  = f4 & 7;
        const float4 v = *reinterpret_cast<const float4*>(We + (size_t)i * J_ + j0 + c * 4);
        float* p = &Wf[i * 33 + c * 4];
        p[0] = v.x; p[1] = v.y; p[2] = v.z; p[3] = v.w;
    }
    __syncthreads();
    char* img = (char*)Wt + (size_t)e * (I_ * J_ * 2);
#pragma unroll
    for (int u2 = 0; u2 < 2; ++u2) {
        const int c  = t + 256 * u2;     // 0..511
        const int jl = c >> 4;
        const int j  = j0 + jl;
        const int i0 = (c & 15) * 8;
        s8v o;
#pragma unroll
        for (int u = 0; u < 8; ++u)
            o[u] = (short)f2bf(Wf[(i0 + u) * 33 + jl]);
        const int cimg = j * 16 + (c & 15);
        *reinterpret_cast<s8v*>(img + ((cimg * 16) ^ ((j & 7) << 4))) = o;
    }
}

// ---- Main (r12 structure): 512 threads / 128 rows; W-stage via DMA ----
// LDS: WsT 32KB + Xs 32KB = 64KB -> 2 blocks/CU = 16 waves/CU.
// ONLY change vs r12: W staged with global_load_lds (linear dest, image
// pre-swizzled in d_ws) instead of per-thread load+swizzled ds_write.
template<bool PRE>
__global__ __launch_bounds__(512, 4)
void gather_mfma(const float* __restrict__ X, const int* __restrict__ ind,
                 const void* __restrict__ Wsrc, float* __restrict__ Y) {
    __shared__ u16 WsT[I_ * J_];
    __shared__ u16 Xs[ROWS * I_];

    const int t    = threadIdx.x;
    const int wave = t >> 6;
    const int lane = t & 63;

    // XCD b-affinity swizzle: grid=1024, 8 XCDs. XCD x gets bid 128x..128x+127
    // -> be in [16x,16x+16) -> exactly batch b=x (X[b] 4MB L2-resident).
    const int orig = blockIdx.x;
    const int bid  = (orig & 7) * 128 + (orig >> 3);
    const int kt = bid & 7;              // K_/ROWS = 8
    const int be = bid >> 3;
    const int e  = be & (E_ - 1);
    const int b  = be >> 4;
    const int k0 = kt * ROWS;

    // X gather geometry (issue the index load first: longest dependency chain)
    const int r   = t >> 2;              // row 0..127
    const int q   = t & 3;               // 32-elem quarter
    const int idx = ind[(size_t)be * K_ + k0 + r];

    // ---- Stage WsT ----
    if (PRE) {
        // Pure DMA: pre-swizzled image -> linear LDS copy, 4 gload/wave.
        const char* Wimg = (const char*)Wsrc + (size_t)e * 32768;
#pragma unroll
        for (int u = 0; u < 4; ++u) {
            const int off = (wave * 4 + u) * 1024;   // wave-uniform LDS dest
            gload_lds16(Wimg + off + lane * 16, (char*)WsT + off);
        }
    } else {
        // Fallback: transpose+convert W[e] (f32 [i][j]) inline.
        const float* We = (const float*)Wsrc + (size_t)e * (I_ * J_);
#pragma unroll
        for (int u = 0; u < 8; ++u) {
            const int f4i = t + 512 * u;          // float4 id, 0..4095
            const int i   = f4i >> 5;
            const int j0  = (f4i & 31) * 4;
            const float4 w4 = reinterpret_cast<const float4*>(We)[f4i];
            const float ws[4] = {w4.x, w4.y, w4.z, w4.w};
#pragma unroll
            for (int qq = 0; qq < 4; ++qq) {
                const int j = j0 + qq;
                *(u16*)((char*)WsT + ((j * 256 + i * 2) ^ ((j & 7) << 4))) = f2bf(ws[qq]);
            }
        }
    }

    // ---- Stage Xs: gather 128 rows, convert f32->bf16 (r12 verbatim) ----
    {
        const float4* Xr = reinterpret_cast<const float4*>(X + ((size_t)b * T_ + idx) * I_) + q * 8;
        const int sx = (r & 7) << 4;
        char* xrow = (char*)Xs + r * 256;
#pragma unroll
        for (int u = 0; u < 4; ++u) {
            const float4 a = Xr[2 * u], c = Xr[2 * u + 1];
            s8v o;
            o[0] = (short)f2bf(a.x); o[1] = (short)f2bf(a.y);
            o[2] = (short)f2bf(a.z); o[3] = (short)f2bf(a.w);
            o[4] = (short)f2bf(c.x); o[5] = (short)f2bf(c.y);
            o[6] = (short)f2bf(c.z); o[7] = (short)f2bf(c.w);
            *reinterpret_cast<s8v*>(xrow + ((q * 64 + u * 16) ^ sx)) = o;
        }
    }
    __syncthreads();     // drains vmcnt (W DMA) + lgkm (X ds_writes)

    // ---- Compute (r12 verbatim): wave = (rq, jh); 32 rows x 64 cols ----
    const int rq  = wave >> 1;          // 0..3
    const int jh  = wave & 1;
    const int g   = lane >> 4;
    const int l15 = lane & 15;
    const int sx  = (lane & 7) << 4;

    f4v acc[2][4];
#pragma unroll
    for (int tr = 0; tr < 2; ++tr)
#pragma unroll
        for (int n = 0; n < 4; ++n)
#pragma unroll
            for (int rr = 0; rr < 4; ++rr) acc[tr][n][rr] = 0.f;

    const char* xb = (const char*)Xs  + (size_t)(rq * 32 + l15) * 256;
    const char* wb = (const char*)WsT + (size_t)(jh * 64 + l15) * 256;
#pragma unroll
    for (int s = 0; s < 4; ++s) {
        const int off = (s * 64 + g * 16) ^ sx;
        const s8v a0 = *reinterpret_cast<const s8v*>(xb + off);
        const s8v a1 = *reinterpret_cast<const s8v*>(xb + 16 * 256 + off);
#pragma unroll
        for (int n = 0; n < 4; ++n) {
            const s8v bf = *reinterpret_cast<const s8v*>(wb + n * 16 * 256 + off);
            acc[0][n] = __builtin_amdgcn_mfma_f32_16x16x32_bf16(a0, bf, acc[0][n], 0, 0, 0);
            acc[1][n] = __builtin_amdgcn_mfma_f32_16x16x32_bf16(a1, bf, acc[1][n], 0, 0, 0);
        }
    }

    // ---- Store (r12 verbatim): C/D col = lane&15 -> j, row = 4g+reg -> k ----
    float* Yb = Y + ((size_t)be * K_ + k0) * J_;
#pragma unroll
    for (int tr = 0; tr < 2; ++tr)
#pragma unroll
        for (int n = 0; n < 4; ++n) {
            const int col = jh * 64 + n * 16 + l15;
            const int row0 = rq * 32 + tr * 16 + g * 4;
#pragma unroll
            for (int rr = 0; rr < 4; ++rr)
                Yb[(size_t)(row0 + rr) * J_ + col] = acc[tr][n][rr];
        }
}

extern "C" void kernel_launch(void* const* d_in, const int* in_sizes, int n_in,
                              void* d_out, int out_size, void* d_ws, size_t ws_size,
                              hipStream_t stream) {
    (void)in_sizes; (void)n_in; (void)out_size;
    const float* X   = (const float*)d_in[0];
    const int*   ind = (const int*)d_in[1];
    const float* W   = (const float*)d_in[2];
    float*       Y   = (float*)d_out;

    const size_t wt_bytes = (size_t)E_ * I_ * J_ * sizeof(u16);  // 512 KB
    const int grid = B_ * E_ * (K_ / ROWS);                       // 1024

    if (ws_size >= wt_bytes && d_ws != nullptr) {
        u16* Wt = (u16*)d_ws;
        hipLaunchKernelGGL(convert_wt, dim3(E_ * 4), dim3(256), 0, stream, W, Wt);
        hipLaunchKernelGGL((gather_mfma<true>), dim3(grid), dim3(512), 0, stream,
                           X, ind, (const void*)Wt, Y);
    } else {
        hipLaunchKernelGGL((gather_mfma<false>), dim3(grid), dim3(512), 0, stream,
                           X, ind, (const void*)W, Y);
    }
}

// Round 16
// 29.847 us; speedup vs baseline: 1.1732x; 1.0300x over previous
//
#include <hip/hip_runtime.h>

// Y[b,e,k,j] = sum_i X[b, ind[b,e,k], i] * W[e,i,j]
// X:[B,T,I] f32, ind:[B,E,K] int32, W:[E,I,J] f32 -> Y:[B,E,K,J] f32
#define B_ 8
#define T_ 8192
#define I_ 128
#define E_ 16
#define J_ 128
#define K_ 1024
#define ROWS 128   // k-rows per block (512 threads)

typedef unsigned short u16;
typedef unsigned int   u32;
typedef __attribute__((ext_vector_type(8))) short s8v;   // 8 bf16 = 4 VGPRs
typedef __attribute__((ext_vector_type(4))) float f4v;   // MFMA accumulator

__device__ __forceinline__ u16 f2bf(float f) {
    union { float f; u32 u; } v; v.f = f;
    const u32 u = v.u;
    return (u16)((u + 0x7fffu + ((u >> 16) & 1u)) >> 16);  // RNE, branch-free
}

// ---- Prepass (r8/r12 verbatim): Wt[e][j][i] = bf16(W[e][i][j]), linear ----
__global__ void convert_wt(const float* __restrict__ W, u16* __restrict__ Wt) {
    const int t  = blockIdx.x * 256 + threadIdx.x;  // 32768 threads
    const int o8 = t * 8;                           // 8 outputs along i
    const int e  = o8 >> 14;
    const int r  = o8 & 16383;
    const int j  = r >> 7;
    const int i0 = r & 127;
    const float* Wp = W + e * (I_ * J_) + j;        // column j of W[e]
    s8v o;
#pragma unroll
    for (int u = 0; u < 8; ++u)
        o[u] = (short)f2bf(Wp[(i0 + u) * J_]);
    *reinterpret_cast<s8v*>(Wt + o8) = o;
}

// ---- Main (r12 structure): 512 threads / 128 rows ----
// LDS: WsT 32KB + Xs 32KB = 64KB -> 2 blocks/CU = 16 waves/CU.
// ONLY change vs r12: A-fragments hoisted to registers; compute/store loop
// reordered per n-tile {4 B-reads, 8 MFMA, 8 stores} so stores interleave
// with MFMA instead of bursting after all 32 MFMAs.
template<bool PRE>
__global__ __launch_bounds__(512, 4)
void gather_mfma(const float* __restrict__ X, const int* __restrict__ ind,
                 const void* __restrict__ Wsrc, float* __restrict__ Y) {
    __shared__ u16 WsT[I_ * J_];
    __shared__ u16 Xs[ROWS * I_];

    const int t    = threadIdx.x;
    const int wave = t >> 6;
    const int lane = t & 63;

    // XCD b-affinity swizzle: grid=1024, 8 XCDs. XCD x gets bid 128x..128x+127
    // -> be in [16x,16x+16) -> exactly batch b=x (X[b] 4MB L2-resident).
    const int orig = blockIdx.x;
    const int bid  = (orig & 7) * 128 + (orig >> 3);
    const int kt = bid & 7;              // K_/ROWS = 8
    const int be = bid >> 3;
    const int e  = be & (E_ - 1);
    const int b  = be >> 4;
    const int k0 = kt * ROWS;

    // ---- Stage WsT (r12 verbatim): Wt bf16 [j][i]; swizzled ds_writes ----
    if (PRE) {
        const s8v* Wg = reinterpret_cast<const s8v*>((const u16*)Wsrc + (size_t)e * (I_ * J_));
#pragma unroll
        for (int u = 0; u < 4; ++u) {
            const int c   = t + 512 * u;          // 16B chunk id, 0..2047
            const int row = c >> 4;               // j
            const s8v v = Wg[c];
            *reinterpret_cast<s8v*>((char*)WsT + ((c * 16) ^ ((row & 7) << 4))) = v;
        }
    } else {
        const float* We = (const float*)Wsrc + (size_t)e * (I_ * J_);
#pragma unroll
        for (int u = 0; u < 8; ++u) {
            const int f4i = t + 512 * u;          // float4 id, 0..4095
            const int i   = f4i >> 5;
            const int j0  = (f4i & 31) * 4;
            const float4 w4 = reinterpret_cast<const float4*>(We)[f4i];
            const float ws[4] = {w4.x, w4.y, w4.z, w4.w};
#pragma unroll
            for (int q = 0; q < 4; ++q) {
                const int j = j0 + q;
                *(u16*)((char*)WsT + ((j * 256 + i * 2) ^ ((j & 7) << 4))) = f2bf(ws[q]);
            }
        }
    }

    // ---- Stage Xs: gather 128 rows, convert f32->bf16 (r12 verbatim) ----
    {
        const int r   = t >> 2;                   // row 0..127
        const int q   = t & 3;                    // 32-elem quarter
        const int idx = ind[(size_t)be * K_ + k0 + r];
        const float4* Xr = reinterpret_cast<const float4*>(X + ((size_t)b * T_ + idx) * I_) + q * 8;
        const int sx = (r & 7) << 4;
        char* xrow = (char*)Xs + r * 256;
#pragma unroll
        for (int u = 0; u < 4; ++u) {
            const float4 a = Xr[2 * u], c = Xr[2 * u + 1];
            s8v o;
            o[0] = (short)f2bf(a.x); o[1] = (short)f2bf(a.y);
            o[2] = (short)f2bf(a.z); o[3] = (short)f2bf(a.w);
            o[4] = (short)f2bf(c.x); o[5] = (short)f2bf(c.y);
            o[6] = (short)f2bf(c.z); o[7] = (short)f2bf(c.w);
            *reinterpret_cast<s8v*>(xrow + ((q * 64 + u * 16) ^ sx)) = o;
        }
    }
    __syncthreads();

    // ---- Compute: wave = (row-quarter rq, j-half jh); 32 rows x 64 cols ----
    const int rq  = wave >> 1;          // 0..3
    const int jh  = wave & 1;
    const int g   = lane >> 4;
    const int l15 = lane & 15;
    const int sx  = (lane & 7) << 4;

    const char* xb = (const char*)Xs  + (size_t)(rq * 32 + l15) * 256;
    const char* wb = (const char*)WsT + (size_t)(jh * 64 + l15) * 256;

    // Hoist all A-fragments (8 x s8v = 32 VGPR)
    s8v af[2][4];
#pragma unroll
    for (int s = 0; s < 4; ++s) {
        const int off = (s * 64 + g * 16) ^ sx;
        af[0][s] = *reinterpret_cast<const s8v*>(xb + off);
        af[1][s] = *reinterpret_cast<const s8v*>(xb + 16 * 256 + off);
    }

    float* Yb = Y + ((size_t)be * K_ + k0) * J_;
    // Per n-tile: 4 B-reads, 8 MFMA, 8 scalar stores — steady stream.
#pragma unroll
    for (int n = 0; n < 4; ++n) {
        f4v acc0, acc1;
#pragma unroll
        for (int rr = 0; rr < 4; ++rr) { acc0[rr] = 0.f; acc1[rr] = 0.f; }
#pragma unroll
        for (int s = 0; s < 4; ++s) {
            const int off = (s * 64 + g * 16) ^ sx;
            const s8v bf = *reinterpret_cast<const s8v*>(wb + n * 16 * 256 + off);
            acc0 = __builtin_amdgcn_mfma_f32_16x16x32_bf16(af[0][s], bf, acc0, 0, 0, 0);
            acc1 = __builtin_amdgcn_mfma_f32_16x16x32_bf16(af[1][s], bf, acc1, 0, 0, 0);
        }
        const int col = jh * 64 + n * 16 + l15;
        const int row0 = rq * 32 + g * 4;
#pragma unroll
        for (int rr = 0; rr < 4; ++rr)
            Yb[(size_t)(row0 + rr) * J_ + col] = acc0[rr];
#pragma unroll
        for (int rr = 0; rr < 4; ++rr)
            Yb[(size_t)(row0 + 16 + rr) * J_ + col] = acc1[rr];
    }
}

extern "C" void kernel_launch(void* const* d_in, const int* in_sizes, int n_in,
                              void* d_out, int out_size, void* d_ws, size_t ws_size,
                              hipStream_t stream) {
    (void)in_sizes; (void)n_in; (void)out_size;
    const float* X   = (const float*)d_in[0];
    const int*   ind = (const int*)d_in[1];
    const float* W   = (const float*)d_in[2];
    float*       Y   = (float*)d_out;

    const size_t wt_bytes = (size_t)E_ * I_ * J_ * sizeof(u16);  // 512 KB
    const int grid = B_ * E_ * (K_ / ROWS);                       // 1024

    if (ws_size >= wt_bytes && d_ws != nullptr) {
        u16* Wt = (u16*)d_ws;
        hipLaunchKernelGGL(convert_wt, dim3(E_ * I_ * J_ / (256 * 8)), dim3(256), 0, stream, W, Wt);
        hipLaunchKernelGGL((gather_mfma<true>), dim3(grid), dim3(512), 0, stream,
                           X, ind, (const void*)Wt, Y);
    } else {
        hipLaunchKernelGGL((gather_mfma<false>), dim3(grid), dim3(512), 0, stream,
                           X, ind, (const void*)W, Y);
    }
}

// Round 17
// 28.755 us; speedup vs baseline: 1.2177x; 1.0380x over previous
//
#include <hip/hip_runtime.h>

// Y[b,e,k,j] = sum_i X[b, ind[b,e,k], i] * W[e,i,j]
// X:[B,T,I] f32, ind:[B,E,K] int32, W:[E,I,J] f32 -> Y:[B,E,K,J] f32
#define B_ 8
#define T_ 8192
#define I_ 128
#define E_ 16
#define J_ 128
#define K_ 1024
#define ROWS 128   // k-rows per block (512 threads)

typedef unsigned short u16;
typedef unsigned int   u32;
typedef __attribute__((ext_vector_type(8))) short s8v;   // 8 bf16 = 4 VGPRs
typedef __attribute__((ext_vector_type(4))) float f4v;   // MFMA accumulator

__device__ __forceinline__ u16 f2bf(float f) {
    union { float f; u32 u; } v; v.f = f;
    const u32 u = v.u;
    return (u16)((u + 0x7fffu + ((u >> 16) & 1u)) >> 16);  // RNE, branch-free
}

// ---- Single-dispatch main: inline W convert + gather + bf16 MFMA GEMM ----
// 512 threads / 128 rows. LDS: WsT 32KB + Xs 32KB = 64KB -> 2 blocks/CU
// (16 waves/CU). vs r16: NO prepass kernel — each block transposes+converts
// its expert's W (64KB f32, coalesced float4, L2-hot: 1MB/XCD working set)
// straight into the swizzled [j][i] LDS image. Saves the prepass dispatch,
// its uncoalesced traffic, and the graph-serialized inter-dispatch gap.
__global__ __launch_bounds__(512, 4)
void gather_mfma(const float* __restrict__ X, const int* __restrict__ ind,
                 const float* __restrict__ W, float* __restrict__ Y) {
    __shared__ u16 WsT[I_ * J_];
    __shared__ u16 Xs[ROWS * I_];

    const int t    = threadIdx.x;
    const int wave = t >> 6;
    const int lane = t & 63;

    // XCD b-affinity swizzle: grid=1024, 8 XCDs. XCD x gets bid 128x..128x+127
    // -> be in [16x,16x+16) -> exactly batch b=x (X[b] 4MB L2-resident).
    const int orig = blockIdx.x;
    const int bid  = (orig & 7) * 128 + (orig >> 3);
    const int kt = bid & 7;              // K_/ROWS = 8
    const int be = bid >> 3;
    const int e  = be & (E_ - 1);
    const int b  = be >> 4;
    const int k0 = kt * ROWS;

    // Issue the gather index load first (longest dependency chain).
    const int r   = t >> 2;              // row 0..127
    const int q   = t & 3;               // 32-elem quarter
    const int idx = ind[(size_t)be * K_ + k0 + r];

    // ---- Stage WsT inline: W[e] f32 [i][j] -> bf16 [j][i], swizzled ----
    {
        const float* We = W + (size_t)e * (I_ * J_);
#pragma unroll
        for (int u = 0; u < 8; ++u) {
            const int f4i = t + 512 * u;          // float4 id, 0..4095
            const int i   = f4i >> 5;
            const int j0  = (f4i & 31) * 4;
            const float4 w4 = reinterpret_cast<const float4*>(We)[f4i];
            const float ws[4] = {w4.x, w4.y, w4.z, w4.w};
#pragma unroll
            for (int qq = 0; qq < 4; ++qq) {
                const int j = j0 + qq;
                *(u16*)((char*)WsT + ((j * 256 + i * 2) ^ ((j & 7) << 4))) = f2bf(ws[qq]);
            }
        }
    }

    // ---- Stage Xs: gather 128 rows, convert f32->bf16 (r12/r16 verbatim) ----
    {
        const float4* Xr = reinterpret_cast<const float4*>(X + ((size_t)b * T_ + idx) * I_) + q * 8;
        const int sx = (r & 7) << 4;
        char* xrow = (char*)Xs + r * 256;
#pragma unroll
        for (int u = 0; u < 4; ++u) {
            const float4 a = Xr[2 * u], c = Xr[2 * u + 1];
            s8v o;
            o[0] = (short)f2bf(a.x); o[1] = (short)f2bf(a.y);
            o[2] = (short)f2bf(a.z); o[3] = (short)f2bf(a.w);
            o[4] = (short)f2bf(c.x); o[5] = (short)f2bf(c.y);
            o[6] = (short)f2bf(c.z); o[7] = (short)f2bf(c.w);
            *reinterpret_cast<s8v*>(xrow + ((q * 64 + u * 16) ^ sx)) = o;
        }
    }
    __syncthreads();

    // ---- Compute (r16 verbatim): wave = (rq, jh); 32 rows x 64 cols ----
    const int rq  = wave >> 1;          // 0..3
    const int jh  = wave & 1;
    const int g   = lane >> 4;
    const int l15 = lane & 15;
    const int sx  = (lane & 7) << 4;

    const char* xb = (const char*)Xs  + (size_t)(rq * 32 + l15) * 256;
    const char* wb = (const char*)WsT + (size_t)(jh * 64 + l15) * 256;

    // Hoist all A-fragments (8 x s8v = 32 VGPR)
    s8v af[2][4];
#pragma unroll
    for (int s = 0; s < 4; ++s) {
        const int off = (s * 64 + g * 16) ^ sx;
        af[0][s] = *reinterpret_cast<const s8v*>(xb + off);
        af[1][s] = *reinterpret_cast<const s8v*>(xb + 16 * 256 + off);
    }

    float* Yb = Y + ((size_t)be * K_ + k0) * J_;
    // Per n-tile: 4 B-reads, 8 MFMA, 8 scalar stores — steady stream.
#pragma unroll
    for (int n = 0; n < 4; ++n) {
        f4v acc0, acc1;
#pragma unroll
        for (int rr = 0; rr < 4; ++rr) { acc0[rr] = 0.f; acc1[rr] = 0.f; }
#pragma unroll
        for (int s = 0; s < 4; ++s) {
            const int off = (s * 64 + g * 16) ^ sx;
            const s8v bf = *reinterpret_cast<const s8v*>(wb + n * 16 * 256 + off);
            acc0 = __builtin_amdgcn_mfma_f32_16x16x32_bf16(af[0][s], bf, acc0, 0, 0, 0);
            acc1 = __builtin_amdgcn_mfma_f32_16x16x32_bf16(af[1][s], bf, acc1, 0, 0, 0);
        }
        const int col = jh * 64 + n * 16 + l15;
        const int row0 = rq * 32 + g * 4;
#pragma unroll
        for (int rr = 0; rr < 4; ++rr)
            Yb[(size_t)(row0 + rr) * J_ + col] = acc0[rr];
#pragma unroll
        for (int rr = 0; rr < 4; ++rr)
            Yb[(size_t)(row0 + 16 + rr) * J_ + col] = acc1[rr];
    }
}

extern "C" void kernel_launch(void* const* d_in, const int* in_sizes, int n_in,
                              void* d_out, int out_size, void* d_ws, size_t ws_size,
                              hipStream_t stream) {
    (void)in_sizes; (void)n_in; (void)out_size; (void)d_ws; (void)ws_size;
    const float* X   = (const float*)d_in[0];
    const int*   ind = (const int*)d_in[1];
    const float* W   = (const float*)d_in[2];
    float*       Y   = (float*)d_out;

    const int grid = B_ * E_ * (K_ / ROWS);   // 1024
    hipLaunchKernelGGL(gather_mfma, dim3(grid), dim3(512), 0, stream,
                       X, ind, W, Y);
}